// Round 6
// baseline (302.047 us; speedup 1.0000x reference)
//
#include <hip/hip_runtime.h>

#define S_LEN 2048
#define NH 16
#define HDIM 128
#define DMODEL 2048

typedef __attribute__((ext_vector_type(8))) short bf16x8;
typedef __attribute__((ext_vector_type(4))) float f32x4;

using gas_cvp = const __attribute__((address_space(1))) void*;
using las_vp  = __attribute__((address_space(3))) void*;

__device__ __forceinline__ unsigned short f2bf(float x) {
  unsigned int u = __builtin_bit_cast(unsigned int, x);
  u += 0x7FFFu + ((u >> 16) & 1u);
  return (unsigned short)(u >> 16);
}
__device__ __forceinline__ float bf2f(unsigned short u) {
  unsigned int x = ((unsigned int)u) << 16;
  return __builtin_bit_cast(float, x);
}
__device__ __forceinline__ unsigned int cvt_pk_bf16(float lo, float hi) {
  unsigned int r;
  asm("v_cvt_pk_bf16_f32 %0, %1, %2" : "=v"(r) : "v"(lo), "v"(hi));
  return r;
}

// ---------- fp32 -> bf16 convert ----------
__global__ __launch_bounds__(256) void cvt_kernel(const float4* __restrict__ in,
                                                  ushort4* __restrict__ out, int n4) {
  int i = blockIdx.x * 256 + threadIdx.x;
  if (i < n4) {
    float4 v = in[i];
    ushort4 r;
    r.x = f2bf(v.x); r.y = f2bf(v.y); r.z = f2bf(v.z); r.w = f2bf(v.w);
    out[i] = r;
  }
}

// ---------- sin/cos table ----------
__global__ __launch_bounds__(256) void sincos_kernel(float2* __restrict__ sc) {
  int i = blockIdx.x * 256 + threadIdx.x;
  int s = i >> 6, j = i & 63;
  float inv_ts = 1.0f / powf(10000.0f, (float)j * (1.0f / 64.0f));
  float ang = (float)s * inv_ts;
  sc[i] = make_float2(sinf(ang), cosf(ang));
}

// ---------- RoPE (+scale), z=0: Q (scaled), z=1: K ----------
__global__ __launch_bounds__(256) void rope8_kernel(const unsigned short* __restrict__ XQ,
                                                    const unsigned short* __restrict__ XK,
                                                    const float2* __restrict__ sc,
                                                    unsigned short* __restrict__ outQ,
                                                    unsigned short* __restrict__ outK,
                                                    float qscale) {
  const unsigned short* X = blockIdx.z ? XK : XQ;
  unsigned short* out = blockIdx.z ? outK : outQ;
  float scale = blockIdx.z ? 1.0f : qscale;
  int i = blockIdx.x * 256 + threadIdx.x;   // [4096][16][8]
  int m = i >> 7;
  int r = i & 127;
  int h = r >> 3, jb = (r & 7) * 8;
  int s = m & (S_LEN - 1);
  size_t base = (size_t)m * DMODEL + h * HDIM + jb;
  int4 x1 = *(const int4*)(X + base);
  int4 x2 = *(const int4*)(X + base + 64);
  const float2* pp = sc + s * 64 + jb;
  int4 o1, o2;
  int* x1w = (int*)&x1; int* x2w = (int*)&x2;
  int* o1w = (int*)&o1; int* o2w = (int*)&o2;
#pragma unroll
  for (int w = 0; w < 4; w++) {
    float a_lo = bf2f((unsigned short)(x1w[w] & 0xffff));
    float a_hi = bf2f((unsigned short)((unsigned int)x1w[w] >> 16));
    float b_lo = bf2f((unsigned short)(x2w[w] & 0xffff));
    float b_hi = bf2f((unsigned short)((unsigned int)x2w[w] >> 16));
    float2 c0 = pp[w * 2], c1 = pp[w * 2 + 1];
    float r1l = (a_lo * c0.y - b_lo * c0.x) * scale;
    float r1h = (a_hi * c1.y - b_hi * c1.x) * scale;
    float r2l = (b_lo * c0.y + a_lo * c0.x) * scale;
    float r2h = (b_hi * c1.y + a_hi * c1.x) * scale;
    o1w[w] = (int)(cvt_pk_bf16(r1l, r1h));
    o2w[w] = (int)(cvt_pk_bf16(r2l, r2h));
  }
  *(int4*)(out + base) = o1;
  *(int4*)(out + base + 64) = o2;
}

// ---------- 2048x2048 weight transpose + convert, 4 weights in one dispatch ----------
__global__ __launch_bounds__(256) void wtrans4_kernel(const float* __restrict__ w0,
                                                      const float* __restrict__ w1,
                                                      const float* __restrict__ w2,
                                                      const float* __restrict__ w3,
                                                      unsigned short* __restrict__ outb) {
  __shared__ float tile[64][65];
  int z = blockIdx.z;
  const float* in = (z == 0) ? w0 : (z == 1) ? w1 : (z == 2) ? w2 : w3;
  unsigned short* out = outb + (size_t)z * DMODEL * DMODEL;
  int c0 = blockIdx.x * 64, r0 = blockIdx.y * 64;
  int tx = threadIdx.x & 63, ty = threadIdx.x >> 6;
#pragma unroll
  for (int i = 0; i < 16; i++) {
    int r = ty + i * 4;
    tile[r][tx] = in[(size_t)(r0 + r) * DMODEL + c0 + tx];
  }
  __syncthreads();
#pragma unroll
  for (int i = 0; i < 16; i++) {
    int c = ty + i * 4;
    out[(size_t)(c0 + c) * DMODEL + r0 + tx] = f2bf(tile[tx][c]);
  }
}

// ---------- V transpose: [B,S,H,HD] bf16 -> [B,H,HD,S] bf16 ----------
__global__ __launch_bounds__(256) void vtrans_kernel(const unsigned short* __restrict__ vf,
                                                     unsigned short* __restrict__ Vt) {
  __shared__ unsigned short tile[64][65];
  int z = blockIdx.z; int b = z >> 4, h = z & 15;
  const unsigned short* I = vf + (size_t)b * S_LEN * DMODEL + h * HDIM;
  unsigned short* O = Vt + (size_t)z * HDIM * S_LEN;
  int s0 = blockIdx.y * 64, f0 = blockIdx.x * 64;
  int tx = threadIdx.x & 63, ty = threadIdx.x >> 6;
#pragma unroll
  for (int i = 0; i < 16; i++) {
    int r = ty + i * 4;
    tile[r][tx] = I[(size_t)(s0 + r) * DMODEL + f0 + tx];
  }
  __syncthreads();
#pragma unroll
  for (int i = 0; i < 16; i++) {
    int c = ty + i * 4;
    O[(size_t)(f0 + c) * S_LEN + s0 + tx] = tile[tx][c];
  }
}

// ---------- 256x256 8-phase bf16 GEMM (m201 structure) ----------
// C[m][n] = sum_k A[m][k]*Bt[n][k].  M=4096, N=2048, K=2048.
// 512 thr = 8 waves (2M x 4N), wave tile 128x64, BK=64.
// LDS 128KB = 2 bufs x { A-half0 16K | A-half1 16K | B-half0 16K | B-half1 16K }.
// XOR swizzle byte^=((row&7)<<4): linear LDS dest + pre-swizzled global source.
// Quarter = 64 rows = 8KB = one 512-thr global_load_lds sweep.
// Region-retire-derived stage schedule (see analysis):
//   ph1: U.A{q1,q3}+U.B{q0..q3} | ph3: T2.A{q0,q2} | ph5: T2.A{q1,q3}+T2.B{all}
//   ph7: U2.A{q0,q2};  guards vmcnt(2) at ph4-end and ph8-end only.
template <bool BF16OUT>
__global__ __launch_bounds__(512, 2) void gemm256_kernel(
    const unsigned short* __restrict__ Aq,
    const unsigned short* __restrict__ Akv,
    const unsigned short* __restrict__ W,   // [z][N][K]
    void* __restrict__ Cb) {                // [z][M][N]
  constexpr int M = 4096, N = 2048, K = 2048, NT = K / 64;
  __shared__ char lds[131072];
  int z = blockIdx.z;
  const unsigned short* A = (z == 0) ? Aq : Akv;
  const unsigned short* Bt = W + (size_t)z * N * K;

  // XCD swizzle: 128 wg per z, 16 contiguous per XCD (2 bm-panels x all bn)
  int wid = blockIdx.y * 8 + blockIdx.x;
  int nid = (wid & 7) * 16 + (wid >> 3);
  int bn = (nid & 7) * 256, bm = (nid >> 3) * 256;

  int tid = threadIdx.x, wave = tid >> 6, lane = tid & 63;
  int lr = lane & 15, lq = lane >> 4;
  int wr = wave >> 2, wc = wave & 3;

  // stage one 64-row quarter (8KB): q in 0..3 of A (isB=0) or B (isB=1)
  auto STAGE_Q = [&](int t, int buf, int isB, int q) {
    int k0 = (t & (NT - 1)) * 64;
    const unsigned short* src = isB ? Bt : A;
    int rbase = (isB ? bn : bm) + q * 64;
    int o = tid * 16;
    int row = o >> 7, colb = o & 127;
    int sc = colb ^ ((row & 7) << 4);
    __builtin_amdgcn_global_load_lds(
        (gas_cvp)(src + (size_t)(rbase + row) * K + k0 + (sc >> 1)),
        (las_vp)(lds + buf * 65536 + isB * 32768 + (q >> 1) * 16384 + (q & 1) * 8192 + wave * 1024),
        16, 0, 0);
  };
  auto STAGE_AA = [&](int t, int buf) { STAGE_Q(t, buf, 0, 0); STAGE_Q(t, buf, 0, 2); };
  auto STAGE_BIG = [&](int t, int buf) {
    STAGE_Q(t, buf, 0, 1); STAGE_Q(t, buf, 0, 3);
    STAGE_Q(t, buf, 1, 0); STAGE_Q(t, buf, 1, 1);
    STAGE_Q(t, buf, 1, 2); STAGE_Q(t, buf, 1, 3);
  };

  auto LDA = [&](int buf, int m, int kk) -> bf16x8 {   // m 0..7 within wave
    int row = wr * 128 + m * 16 + lr;
    int half = row >> 7, r = row & 127;
    return *(const bf16x8*)(lds + buf * 65536 + half * 16384 + r * 128 +
                            (((kk * 4 + lq) ^ (r & 7)) << 4));
  };
  auto LDB = [&](int buf, int n, int kk) -> bf16x8 {   // n 0..3 within wave
    int row = wc * 64 + n * 16 + lr;
    int half = row >> 7, r = row & 127;
    return *(const bf16x8*)(lds + buf * 65536 + 32768 + half * 16384 + r * 128 +
                            (((kk * 4 + lq) ^ (r & 7)) << 4));
  };

  f32x4 acc[8][4] = {};
  bf16x8 aA[4][2], bB[4][2];

  auto DS_A = [&](int buf, int mg) {
#pragma unroll
    for (int kk = 0; kk < 2; kk++)
#pragma unroll
      for (int mm = 0; mm < 4; mm++) aA[mm][kk] = LDA(buf, mg * 4 + mm, kk);
  };
  auto DS_B = [&](int buf, int ng) {
#pragma unroll
    for (int kk = 0; kk < 2; kk++)
#pragma unroll
      for (int nn = 0; nn < 2; nn++) bB[ng * 2 + nn][kk] = LDB(buf, ng * 2 + nn, kk);
  };
  auto MFMA_Q = [&](int mg, int ng) {
#pragma unroll
    for (int kk = 0; kk < 2; kk++)
#pragma unroll
      for (int mm = 0; mm < 4; mm++)
#pragma unroll
        for (int nn = 0; nn < 2; nn++)
          acc[mg * 4 + mm][ng * 2 + nn] = __builtin_amdgcn_mfma_f32_16x16x32_bf16(
              aA[mm][kk], bB[ng * 2 + nn][kk], acc[mg * 4 + mm][ng * 2 + nn], 0, 0, 0);
  };
  auto PH_MID = [&]() {
    __builtin_amdgcn_s_barrier();
    asm volatile("s_waitcnt lgkmcnt(0)" ::: "memory");
    __builtin_amdgcn_sched_barrier(0);
    __builtin_amdgcn_s_setprio(1);
  };
  auto PH_ENDP = [&]() {
    __builtin_amdgcn_s_setprio(0);
    __builtin_amdgcn_s_barrier();
  };
  auto PH_END_VM2 = [&]() {
    __builtin_amdgcn_s_setprio(0);
    asm volatile("s_waitcnt vmcnt(2)" ::: "memory");
    __builtin_amdgcn_sched_barrier(0);
    __builtin_amdgcn_s_barrier();
  };

  // prologue: T0 full (8 loads) + T1 A{q0,q2} (the ph7-slot item)
  STAGE_AA(0, 0); STAGE_BIG(0, 0);
  STAGE_AA(1, 1);
  asm volatile("s_waitcnt vmcnt(2)" ::: "memory");   // T0 landed; T1.Aa in flight
  __builtin_amdgcn_sched_barrier(0);
  __builtin_amdgcn_s_barrier();

  for (int i = 0; i < NT / 2; i++) {
    int T = 2 * i, U = T + 1;
    int t2 = (T + 2) & (NT - 1), u2 = (U + 2) & (NT - 1);
    // ph1: Q(0,0) of T (buf0)
    DS_A(0, 0); DS_B(0, 0);
    STAGE_BIG(U, 1);
    PH_MID(); MFMA_Q(0, 0); PH_ENDP();
    // ph2: Q(0,1)
    DS_B(0, 1);
    PH_MID(); MFMA_Q(0, 1); PH_ENDP();
    // ph3: Q(1,0)
    DS_A(0, 1);
    STAGE_AA(t2, 0);
    PH_MID(); MFMA_Q(1, 0); PH_ENDP();
    // ph4: Q(1,1)  [guard: confirms ph1's 6 for ph5's buf1 reads]
    PH_MID(); MFMA_Q(1, 1); PH_END_VM2();
    // ph5: Q(0,0) of U (buf1)
    DS_A(1, 0); DS_B(1, 0);
    STAGE_BIG(t2, 0);
    PH_MID(); MFMA_Q(0, 0); PH_ENDP();
    // ph6: Q(0,1)
    DS_B(1, 1);
    PH_MID(); MFMA_Q(0, 1); PH_ENDP();
    // ph7: Q(1,0)
    DS_A(1, 1);
    STAGE_AA(u2, 1);
    PH_MID(); MFMA_Q(1, 0); PH_ENDP();
    // ph8: Q(1,1)  [guard: confirms ph3+ph5 for next ph1's buf0 reads]
    PH_MID(); MFMA_Q(1, 1); PH_END_VM2();
  }
  asm volatile("s_waitcnt vmcnt(0)" ::: "memory");

  // epilogue: rows = bm + wr*128 + m*16 + lq*4 + r; cols = bn + wc*64 + n*16 + lr
#pragma unroll
  for (int m = 0; m < 8; m++)
#pragma unroll
    for (int n = 0; n < 4; n++) {
      int row0 = bm + wr * 128 + m * 16 + lq * 4;
      int col = bn + wc * 64 + n * 16 + lr;
      if (BF16OUT) {
        unsigned short* C = (unsigned short*)Cb + (size_t)z * M * N;
#pragma unroll
        for (int r = 0; r < 4; r++)
          C[(size_t)(row0 + r) * N + col] = f2bf(acc[m][n][r]);
      } else {
        float* C = (float*)Cb + (size_t)z * M * N;
#pragma unroll
        for (int r = 0; r < 4; r++)
          C[(size_t)(row0 + r) * N + col] = acc[m][n][r];
      }
    }
}

// ---------- causal flash attention, swapped-QK^T in-register softmax ----------
__global__ __launch_bounds__(512, 1) void attn_kernel(const unsigned short* __restrict__ Qb,
                                                      const unsigned short* __restrict__ Kb,
                                                      const unsigned short* __restrict__ Vt,
                                                      unsigned short* __restrict__ ctx) {
  __shared__ char lds[65536];   // dbuf: [2][ K 16KB | V^T 16KB ]
  int d = blockIdx.x + 8 * (blockIdx.y + 16 * blockIdx.z);
  int jlo = (d >> 3) & 7;
  int hb = (d & 7) * 4 + (d >> 6);
  int h = hb & 15, b = hb >> 4;

  int tid = threadIdx.x, wave = tid >> 6, lane = tid & 63;
  int lr = lane & 15, lq = lane >> 4;
  int grp = wave >> 2, wsub = wave & 3;
  int qtile = grp ? (15 - jlo) : jlo;
  int qw = qtile * 128 + wsub * 32;
  int nt = 2 * (15 - jlo) + 2;

  const unsigned short* Qp = Qb + (size_t)b * S_LEN * DMODEL + (size_t)h * HDIM;
  const unsigned short* Kp = Kb + (size_t)b * S_LEN * DMODEL + (size_t)h * HDIM;
  const unsigned short* Vp = Vt + (size_t)(b * NH + h) * HDIM * S_LEN;

  bf16x8 qa[2][4];
#pragma unroll
  for (int mi = 0; mi < 2; mi++)
#pragma unroll
    for (int kf = 0; kf < 4; kf++)
      qa[mi][kf] = *(const bf16x8*)(Qp + (size_t)(qw + mi * 16 + lr) * DMODEL + kf * 32 + lq * 8);

  f32x4 o[2][8] = {};
  float mrow[2] = {-1e30f, -1e30f};
  float lsum[2] = {0.f, 0.f};

  auto STAGE = [&](int tt, int bsel) {
    int kk0 = tt * 64;
#pragma unroll
    for (int i = 0; i < 2; i++) {             // K tile [64][128] bf16, 16KB
      int o_ = wave * 2048 + i * 1024 + lane * 16;
      int row = o_ >> 8, colb = o_ & 255;
      int sc_ = colb ^ ((row & 7) << 4);
      __builtin_amdgcn_global_load_lds(
          (gas_cvp)(Kp + (size_t)(kk0 + row) * DMODEL + (sc_ >> 1)),
          (las_vp)(lds + bsel * 32768 + wave * 2048 + i * 1024), 16, 0, 0);
    }
#pragma unroll
    for (int i = 0; i < 2; i++) {             // V^T tile [128][64] bf16, 16KB
      int o_ = wave * 2048 + i * 1024 + lane * 16;
      int row = o_ >> 7, colb = o_ & 127;
      int sc_ = colb ^ ((row & 7) << 4);
      __builtin_amdgcn_global_load_lds(
          (gas_cvp)(Vp + (size_t)row * S_LEN + kk0 + (sc_ >> 1)),
          (las_vp)(lds + bsel * 32768 + 16384 + wave * 2048 + i * 1024), 16, 0, 0);
    }
  };

  STAGE(0, 0);
  __syncthreads();

  for (int t = 0; t < nt; t++) {
    int cur = t & 1;
    int k0 = t * 64;
    if (t + 1 < nt) STAGE(t + 1, cur ^ 1);

    bool active = (k0 <= qw + 31);
    if (active) {
      const char* kbb = lds + cur * 32768;
      f32x4 sf[2][4] = {};
#pragma unroll
      for (int kf = 0; kf < 4; kf++) {
        bf16x8 kbf[4];
#pragma unroll
        for (int nf = 0; nf < 4; nf++) {
          int row = nf * 16 + lr;
          int colb = kf * 64 + lq * 16;
          kbf[nf] = *(const bf16x8*)(kbb + row * 256 + (colb ^ ((row & 7) << 4)));
        }
#pragma unroll
        for (int nf = 0; nf < 4; nf++)
#pragma unroll
          for (int mi = 0; mi < 2; mi++)
            sf[mi][nf] = __builtin_amdgcn_mfma_f32_16x16x32_bf16(kbf[nf], qa[mi][kf], sf[mi][nf], 0, 0, 0);
      }

      if (k0 + 63 > qw) {
#pragma unroll
        for (int mi = 0; mi < 2; mi++) {
          int q = qw + mi * 16 + lr;
#pragma unroll
          for (int nf = 0; nf < 4; nf++)
#pragma unroll
            for (int r = 0; r < 4; r++)
              if (k0 + nf * 16 + lq * 4 + r > q) sf[mi][nf][r] = -1e30f;
        }
      }

      float vmax[2];
#pragma unroll
      for (int mi = 0; mi < 2; mi++) {
        float v = sf[mi][0][0];
#pragma unroll
        for (int nf = 0; nf < 4; nf++)
#pragma unroll
          for (int r = 0; r < 4; r++) v = fmaxf(v, sf[mi][nf][r]);
        v = fmaxf(v, __shfl_xor(v, 16));
        v = fmaxf(v, __shfl_xor(v, 32));
        vmax[mi] = v;
      }
      bool need = (vmax[0] > mrow[0] + 8.f) || (vmax[1] > mrow[1] + 8.f);
      if (__any(need)) {
#pragma unroll
        for (int mi = 0; mi < 2; mi++) {
          float mn = fmaxf(mrow[mi], vmax[mi]);
          float al = __expf(mrow[mi] - mn);
          mrow[mi] = mn;
          lsum[mi] *= al;
#pragma unroll
          for (int ff = 0; ff < 8; ff++) o[mi][ff] *= al;
        }
      }
#pragma unroll
      for (int mi = 0; mi < 2; mi++) {
        float rs = 0.f;
#pragma unroll
        for (int nf = 0; nf < 4; nf++)
#pragma unroll
          for (int r = 0; r < 4; r++) {
            float p = __expf(sf[mi][nf][r] - mrow[mi]);
            sf[mi][nf][r] = p;
            rs += p;
          }
        rs += __shfl_xor(rs, 16);
        rs += __shfl_xor(rs, 32);
        lsum[mi] += rs;
      }

      const char* vbb = lds + cur * 32768 + 16384;
      bool hi = (lane >= 32);
      bool odd = (lq & 1);
#pragma unroll
      for (int c = 0; c < 2; c++) {
        bf16x8 pfrag[2];
#pragma unroll
        for (int mi = 0; mi < 2; mi++) {
          unsigned int A0 = cvt_pk_bf16(sf[mi][2 * c][0], sf[mi][2 * c][1]);
          unsigned int A1 = cvt_pk_bf16(sf[mi][2 * c][2], sf[mi][2 * c][3]);
          unsigned int B0 = cvt_pk_bf16(sf[mi][2 * c + 1][0], sf[mi][2 * c + 1][1]);
          unsigned int B1 = cvt_pk_bf16(sf[mi][2 * c + 1][2], sf[mi][2 * c + 1][3]);
          unsigned int sA0 = (unsigned int)__shfl_xor((int)A0, 32);
          unsigned int sA1 = (unsigned int)__shfl_xor((int)A1, 32);
          unsigned int sB0 = (unsigned int)__shfl_xor((int)B0, 32);
          unsigned int sB1 = (unsigned int)__shfl_xor((int)B1, 32);
          unsigned int Y0f = hi ? sB0 : A0, Y0s = hi ? B0 : sA0;
          unsigned int Y1f = hi ? sB1 : A1, Y1s = hi ? B1 : sA1;
          unsigned int z0 = odd ? Y0f : Y0s, z1 = odd ? Y1f : Y1s;
          unsigned int w0 = (unsigned int)__shfl_xor((int)z0, 16);
          unsigned int w1 = (unsigned int)__shfl_xor((int)z1, 16);
          int4 fr;
          fr.x = (int)(odd ? w0 : Y0f);
          fr.y = (int)(odd ? w1 : Y1f);
          fr.z = (int)(odd ? Y0s : w0);
          fr.w = (int)(odd ? Y1s : w1);
          pfrag[mi] = __builtin_bit_cast(bf16x8, fr);
        }
#pragma unroll
        for (int ff = 0; ff < 8; ff++) {
          int row = ff * 16 + lr;
          int colb = c * 64 + lq * 16;
          bf16x8 vb = *(const bf16x8*)(vbb + row * 128 + (colb ^ ((row & 7) << 4)));
#pragma unroll
          for (int mi = 0; mi < 2; mi++)
            o[mi][ff] = __builtin_amdgcn_mfma_f32_16x16x32_bf16(vb, pfrag[mi], o[mi][ff], 0, 0, 0);
        }
      }
    }

    __syncthreads();
  }

#pragma unroll
  for (int mi = 0; mi < 2; mi++) {
    float inv = 1.0f / lsum[mi];
    size_t rb = ((size_t)b * S_LEN + qw + mi * 16 + lr) * DMODEL + h * HDIM;
#pragma unroll
    for (int ff = 0; ff < 8; ff++) {
      unsigned int u0 = cvt_pk_bf16(o[mi][ff][0] * inv, o[mi][ff][1] * inv);
      unsigned int u1 = cvt_pk_bf16(o[mi][ff][2] * inv, o[mi][ff][3] * inv);
      *(uint2*)(ctx + rb + ff * 16 + lq * 4) = make_uint2(u0, u1);
    }
  }
}

extern "C" void kernel_launch(void* const* d_in, const int* in_sizes, int n_in,
                              void* d_out, int out_size, void* d_ws, size_t ws_size,
                              hipStream_t stream) {
  const float* inq  = (const float*)d_in[0];
  const float* inkv = (const float*)d_in[1];
  const float* wq   = (const float*)d_in[2];
  const float* wk   = (const float*)d_in[3];
  const float* wv   = (const float*)d_in[4];
  const float* wo   = (const float*)d_in[5];
  float* out = (float*)d_out;

  char* ws = (char*)d_ws;
  const size_t MB = 1ull << 20;
  unsigned short* xq  = (unsigned short*)(ws);             // 16 MB (reused as Qb)
  unsigned short* xkv = (unsigned short*)(ws + 16 * MB);   // 16 MB (reused as Kb)
  unsigned short* wqt = (unsigned short*)(ws + 32 * MB);   // 8 MB
  unsigned short* wot = (unsigned short*)(ws + 56 * MB);   // 8 MB (wqt..wot contiguous)
  float2* sc          = (float2*)(ws + 64 * MB);           // 1 MB
  unsigned short* projb = (unsigned short*)(ws + 66 * MB); // 48 MB (Q,K,V bf16)
  unsigned short* Vt   = (unsigned short*)(ws + 114 * MB); // 16 MB
  unsigned short* ctxb = (unsigned short*)(ws + 130 * MB); // 16 MB
  unsigned short* Qb = xq;    // xq dead after proj GEMM
  unsigned short* Kb = xkv;   // xkv dead after proj GEMM

  const int n4 = (2 * S_LEN * DMODEL) / 4;
  cvt_kernel<<<n4 / 256, 256, 0, stream>>>((const float4*)inq, (ushort4*)xq, n4);
  cvt_kernel<<<n4 / 256, 256, 0, stream>>>((const float4*)inkv, (ushort4*)xkv, n4);

  wtrans4_kernel<<<dim3(32, 32, 4), 256, 0, stream>>>(wq, wk, wv, wo, wqt);

  sincos_kernel<<<(S_LEN * 64) / 256, 256, 0, stream>>>(sc);

  const float qscale = 0.08838834764831845f;  // 1/sqrt(128)
  unsigned short* projQ = projb;
  unsigned short* projK = projb + (size_t)4096 * 2048;
  unsigned short* projV = projb + (size_t)2 * 4096 * 2048;

  // all three projections in one dispatch (z = op); 384 blocks
  gemm256_kernel<true><<<dim3(8, 16, 3), 512, 0, stream>>>(xq, xkv, wqt, (void*)projb);

  rope8_kernel<<<dim3(2048, 1, 2), 256, 0, stream>>>(projQ, projK, sc, Qb, Kb, qscale);
  vtrans_kernel<<<dim3(2, 32, 32), 256, 0, stream>>>(projV, Vt);

  attn_kernel<<<dim3(8, NH, 2), 512, 0, stream>>>(Qb, Kb, Vt, ctxb);

  // output projection: 128 blocks
  gemm256_kernel<false><<<dim3(8, 16, 1), 512, 0, stream>>>(ctxb, ctxb, wot, (void*)out);
}

// Round 7
// 285.152 us; speedup vs baseline: 1.0593x; 1.0593x over previous
//
#include <hip/hip_runtime.h>

#define S_LEN 2048
#define NH 16
#define HDIM 128
#define DMODEL 2048

typedef __attribute__((ext_vector_type(8))) short bf16x8;
typedef __attribute__((ext_vector_type(4))) float f32x4;

using gas_cvp = const __attribute__((address_space(1))) void*;
using las_vp  = __attribute__((address_space(3))) void*;

__device__ __forceinline__ unsigned short f2bf(float x) {
  unsigned int u = __builtin_bit_cast(unsigned int, x);
  u += 0x7FFFu + ((u >> 16) & 1u);
  return (unsigned short)(u >> 16);
}
__device__ __forceinline__ float bf2f(unsigned short u) {
  unsigned int x = ((unsigned int)u) << 16;
  return __builtin_bit_cast(float, x);
}
__device__ __forceinline__ unsigned int cvt_pk_bf16(float lo, float hi) {
  unsigned int r;
  asm("v_cvt_pk_bf16_f32 %0, %1, %2" : "=v"(r) : "v"(lo), "v"(hi));
  return r;
}

// ---------- fp32 -> bf16 convert ----------
__global__ __launch_bounds__(256) void cvt_kernel(const float4* __restrict__ in,
                                                  ushort4* __restrict__ out, int n4) {
  int i = blockIdx.x * 256 + threadIdx.x;
  if (i < n4) {
    float4 v = in[i];
    ushort4 r;
    r.x = f2bf(v.x); r.y = f2bf(v.y); r.z = f2bf(v.z); r.w = f2bf(v.w);
    out[i] = r;
  }
}

// ---------- sin/cos table ----------
__global__ __launch_bounds__(256) void sincos_kernel(float2* __restrict__ sc) {
  int i = blockIdx.x * 256 + threadIdx.x;
  int s = i >> 6, j = i & 63;
  float inv_ts = 1.0f / powf(10000.0f, (float)j * (1.0f / 64.0f));
  float ang = (float)s * inv_ts;
  sc[i] = make_float2(sinf(ang), cosf(ang));
}

// ---------- RoPE (+scale), z=0: Q (scaled), z=1: K ----------
__global__ __launch_bounds__(256) void rope8_kernel(const unsigned short* __restrict__ XQ,
                                                    const unsigned short* __restrict__ XK,
                                                    const float2* __restrict__ sc,
                                                    unsigned short* __restrict__ outQ,
                                                    unsigned short* __restrict__ outK,
                                                    float qscale) {
  const unsigned short* X = blockIdx.z ? XK : XQ;
  unsigned short* out = blockIdx.z ? outK : outQ;
  float scale = blockIdx.z ? 1.0f : qscale;
  int i = blockIdx.x * 256 + threadIdx.x;   // [4096][16][8]
  int m = i >> 7;
  int r = i & 127;
  int h = r >> 3, jb = (r & 7) * 8;
  int s = m & (S_LEN - 1);
  size_t base = (size_t)m * DMODEL + h * HDIM + jb;
  int4 x1 = *(const int4*)(X + base);
  int4 x2 = *(const int4*)(X + base + 64);
  const float2* pp = sc + s * 64 + jb;
  int4 o1, o2;
  int* x1w = (int*)&x1; int* x2w = (int*)&x2;
  int* o1w = (int*)&o1; int* o2w = (int*)&o2;
#pragma unroll
  for (int w = 0; w < 4; w++) {
    float a_lo = bf2f((unsigned short)(x1w[w] & 0xffff));
    float a_hi = bf2f((unsigned short)((unsigned int)x1w[w] >> 16));
    float b_lo = bf2f((unsigned short)(x2w[w] & 0xffff));
    float b_hi = bf2f((unsigned short)((unsigned int)x2w[w] >> 16));
    float2 c0 = pp[w * 2], c1 = pp[w * 2 + 1];
    float r1l = (a_lo * c0.y - b_lo * c0.x) * scale;
    float r1h = (a_hi * c1.y - b_hi * c1.x) * scale;
    float r2l = (b_lo * c0.y + a_lo * c0.x) * scale;
    float r2h = (b_hi * c1.y + a_hi * c1.x) * scale;
    o1w[w] = (int)(cvt_pk_bf16(r1l, r1h));
    o2w[w] = (int)(cvt_pk_bf16(r2l, r2h));
  }
  *(int4*)(out + base) = o1;
  *(int4*)(out + base + 64) = o2;
}

// ---------- 2048x2048 weight transpose + convert, 4 weights in one dispatch ----------
__global__ __launch_bounds__(256) void wtrans4_kernel(const float* __restrict__ w0,
                                                      const float* __restrict__ w1,
                                                      const float* __restrict__ w2,
                                                      const float* __restrict__ w3,
                                                      unsigned short* __restrict__ outb) {
  __shared__ float tile[64][65];
  int z = blockIdx.z;
  const float* in = (z == 0) ? w0 : (z == 1) ? w1 : (z == 2) ? w2 : w3;
  unsigned short* out = outb + (size_t)z * DMODEL * DMODEL;
  int c0 = blockIdx.x * 64, r0 = blockIdx.y * 64;
  int tx = threadIdx.x & 63, ty = threadIdx.x >> 6;
#pragma unroll
  for (int i = 0; i < 16; i++) {
    int r = ty + i * 4;
    tile[r][tx] = in[(size_t)(r0 + r) * DMODEL + c0 + tx];
  }
  __syncthreads();
#pragma unroll
  for (int i = 0; i < 16; i++) {
    int c = ty + i * 4;
    out[(size_t)(c0 + c) * DMODEL + r0 + tx] = f2bf(tile[tx][c]);
  }
}

// ---------- V transpose: [B,S,H,HD] bf16 -> [B,H,HD,S] bf16 ----------
__global__ __launch_bounds__(256) void vtrans_kernel(const unsigned short* __restrict__ vf,
                                                     unsigned short* __restrict__ Vt) {
  __shared__ unsigned short tile[64][65];
  int z = blockIdx.z; int b = z >> 4, h = z & 15;
  const unsigned short* I = vf + (size_t)b * S_LEN * DMODEL + h * HDIM;
  unsigned short* O = Vt + (size_t)z * HDIM * S_LEN;
  int s0 = blockIdx.y * 64, f0 = blockIdx.x * 64;
  int tx = threadIdx.x & 63, ty = threadIdx.x >> 6;
#pragma unroll
  for (int i = 0; i < 16; i++) {
    int r = ty + i * 4;
    tile[r][tx] = I[(size_t)(s0 + r) * DMODEL + f0 + tx];
  }
  __syncthreads();
#pragma unroll
  for (int i = 0; i < 16; i++) {
    int c = ty + i * 4;
    O[(size_t)(f0 + c) * S_LEN + s0 + tx] = tile[tx][c];
  }
}

// ---------- 256x256 8-phase bf16 GEMM v2 ----------
// Reads/phase 4/8/4/8 with cross-tile pipelined Q(1,1); stages 2/2/0/4 at
// earliest clobber-free slots; single vmcnt(4) guard per K-tile (2-phase lead).
// Queue invariant at each ph4-end: leftover B01(X+1)=4 + {A0,A1(X+1), B01(X+2)}=8;
// vmcnt(4) confirms exactly tile X+1's 8 loads, leaves B01(X+2) in flight.
template <bool BF16OUT>
__global__ __launch_bounds__(512, 2) void gemm256v2_kernel(
    const unsigned short* __restrict__ Aq,
    const unsigned short* __restrict__ Akv,
    const unsigned short* __restrict__ W,   // [z][N][K]
    void* __restrict__ Cb) {                // [z][M][N]
  constexpr int M = 4096, N = 2048, K = 2048, NT = K / 64;
  __shared__ char lds[131072];
  int z = blockIdx.z;
  const unsigned short* A = (z == 0) ? Aq : Akv;
  const unsigned short* Bt = W + (size_t)z * N * K;

  // XCD swizzle: 128 wg per z, 16 contiguous per XCD
  int wid = blockIdx.y * 8 + blockIdx.x;
  int nid = (wid & 7) * 16 + (wid >> 3);
  int bn = (nid & 7) * 256, bm = (nid >> 3) * 256;

  int tid = threadIdx.x, wave = tid >> 6, lane = tid & 63;
  int lr = lane & 15, lq = lane >> 4;
  int wr = wave >> 2, wc = wave & 3;

  // stage one 16KB half-tile (2 loads): isB 0=A 1=B, h 0/1 = 128-row half
  auto STAGE_H = [&](int t, int buf, int isB, int h) {
    int k0 = (t & (NT - 1)) * 64;
    const unsigned short* src = isB ? Bt : A;
    int rbase = (isB ? bn : bm) + h * 128;
    char* dst0 = lds + buf * 65536 + isB * 32768 + h * 16384;
#pragma unroll
    for (int i = 0; i < 2; i++) {
      int o = i * 8192 + tid * 16;
      int row = o >> 7, colb = o & 127;
      int sc = colb ^ ((row & 7) << 4);
      __builtin_amdgcn_global_load_lds(
          (gas_cvp)(src + (size_t)(rbase + row) * K + k0 + (sc >> 1)),
          (las_vp)(dst0 + i * 8192 + wave * 1024), 16, 0, 0);
    }
  };

  auto LDA = [&](int buf, int m, int kk) -> bf16x8 {   // m 0..7 within wave
    int row = wr * 128 + m * 16 + lr;
    int half = row >> 7, r = row & 127;
    return *(const bf16x8*)(lds + buf * 65536 + half * 16384 + r * 128 +
                            (((kk * 4 + lq) ^ (r & 7)) << 4));
  };
  auto LDB = [&](int buf, int n, int kk) -> bf16x8 {   // n 0..3 within wave
    int row = wc * 64 + n * 16 + lr;
    int half = row >> 7, r = row & 127;
    return *(const bf16x8*)(lds + buf * 65536 + 32768 + half * 16384 + r * 128 +
                            (((kk * 4 + lq) ^ (r & 7)) << 4));
  };

  f32x4 acc[8][4] = {};
  bf16x8 aA[4][2], bN0[2][2], bN1[2][2];

  // 16-MFMA quadrants
  auto Q_mg0_n0 = [&]() {
#pragma unroll
    for (int kk = 0; kk < 2; kk++)
#pragma unroll
      for (int mm = 0; mm < 4; mm++)
#pragma unroll
        for (int nn = 0; nn < 2; nn++)
          acc[mm][nn] = __builtin_amdgcn_mfma_f32_16x16x32_bf16(aA[mm][kk], bN0[nn][kk], acc[mm][nn], 0, 0, 0);
  };
  auto Q_mg0_n1 = [&]() {
#pragma unroll
    for (int kk = 0; kk < 2; kk++)
#pragma unroll
      for (int mm = 0; mm < 4; mm++)
#pragma unroll
        for (int nn = 0; nn < 2; nn++)
          acc[mm][2 + nn] = __builtin_amdgcn_mfma_f32_16x16x32_bf16(aA[mm][kk], bN1[nn][kk], acc[mm][2 + nn], 0, 0, 0);
  };
  auto Q_mg1_n0 = [&]() {
#pragma unroll
    for (int kk = 0; kk < 2; kk++)
#pragma unroll
      for (int mm = 0; mm < 4; mm++)
#pragma unroll
        for (int nn = 0; nn < 2; nn++)
          acc[4 + mm][nn] = __builtin_amdgcn_mfma_f32_16x16x32_bf16(aA[mm][kk], bN0[nn][kk], acc[4 + mm][nn], 0, 0, 0);
  };
  auto Q_mg1_n1 = [&]() {   // pipelined: runs in NEXT tile's ph1 from live regs
#pragma unroll
    for (int kk = 0; kk < 2; kk++)
#pragma unroll
      for (int mm = 0; mm < 4; mm++)
#pragma unroll
        for (int nn = 0; nn < 2; nn++)
          acc[4 + mm][2 + nn] = __builtin_amdgcn_mfma_f32_16x16x32_bf16(aA[mm][kk], bN1[nn][kk], acc[4 + mm][2 + nn], 0, 0, 0);
  };

  auto PH_MID = [&]() {
    __builtin_amdgcn_s_barrier();
    asm volatile("s_waitcnt lgkmcnt(0)" ::: "memory");
    __builtin_amdgcn_sched_barrier(0);
    __builtin_amdgcn_s_setprio(1);
  };
  auto PH_ENDP = [&]() {
    __builtin_amdgcn_s_setprio(0);
    __builtin_amdgcn_s_barrier();
  };

  // prologue: T0 all (8 loads) + B01(T1) (4 loads); confirm T0, leave 4 in flight
  STAGE_H(0, 0, 0, 0); STAGE_H(0, 0, 0, 1); STAGE_H(0, 0, 1, 0); STAGE_H(0, 0, 1, 1);
  STAGE_H(1, 1, 1, 0); STAGE_H(1, 1, 1, 1);
  asm volatile("s_waitcnt vmcnt(4)" ::: "memory");
  __builtin_amdgcn_sched_barrier(0);
  __builtin_amdgcn_s_barrier();

  for (int X = 0; X < NT; X++) {
    int c = X & 1, nc = c ^ 1;
    // ph1: read B-ng0(X) [4]; stage A0(X+1); MFMA Q(1,1) of X-1 (regs)
#pragma unroll
    for (int kk = 0; kk < 2; kk++)
#pragma unroll
      for (int nn = 0; nn < 2; nn++) bN0[nn][kk] = LDB(c, nn, kk);
    STAGE_H(X + 1, nc, 0, 0);
    PH_MID();
    if (X) Q_mg1_n1();
    PH_ENDP();

    // ph2: read A-mg0(X) [8]; stage A1(X+1); MFMA Q(0,0)
#pragma unroll
    for (int kk = 0; kk < 2; kk++)
#pragma unroll
      for (int mm = 0; mm < 4; mm++) aA[mm][kk] = LDA(c, mm, kk);
    STAGE_H(X + 1, nc, 0, 1);
    PH_MID(); Q_mg0_n0(); PH_ENDP();

    // ph3: read B-ng1(X) [4]; MFMA Q(0,1)
#pragma unroll
    for (int kk = 0; kk < 2; kk++)
#pragma unroll
      for (int nn = 0; nn < 2; nn++) bN1[nn][kk] = LDB(c, 2 + nn, kk);
    PH_MID(); Q_mg0_n1(); PH_ENDP();

    // ph4: read A-mg1(X) [8]; stage B01(X+2); MFMA Q(1,0); guard vmcnt(4)
#pragma unroll
    for (int kk = 0; kk < 2; kk++)
#pragma unroll
      for (int mm = 0; mm < 4; mm++) aA[mm][kk] = LDA(c, 4 + mm, kk);
    STAGE_H(X + 2, c, 1, 0); STAGE_H(X + 2, c, 1, 1);
    PH_MID(); Q_mg1_n0();
    __builtin_amdgcn_s_setprio(0);
    asm volatile("s_waitcnt vmcnt(4)" ::: "memory");
    __builtin_amdgcn_sched_barrier(0);
    __builtin_amdgcn_s_barrier();
  }
  // tail: Q(1,1) of NT-1 (pure registers)
  Q_mg1_n1();
  asm volatile("s_waitcnt vmcnt(0)" ::: "memory");

  // epilogue
#pragma unroll
  for (int m = 0; m < 8; m++)
#pragma unroll
    for (int n = 0; n < 4; n++) {
      int row0 = bm + wr * 128 + m * 16 + lq * 4;
      int col = bn + wc * 64 + n * 16 + lr;
      if (BF16OUT) {
        unsigned short* C = (unsigned short*)Cb + (size_t)z * M * N;
#pragma unroll
        for (int r = 0; r < 4; r++)
          C[(size_t)(row0 + r) * N + col] = f2bf(acc[m][n][r]);
      } else {
        float* C = (float*)Cb + (size_t)z * M * N;
#pragma unroll
        for (int r = 0; r < 4; r++)
          C[(size_t)(row0 + r) * N + col] = acc[m][n][r];
      }
    }
}

// ---------- triple-buffered 256x128 bf16 GEMM (round-5, for out-proj) ----------
template <bool BF16OUT>
__global__ __launch_bounds__(512) void gemm3b_kernel(
    const unsigned short* __restrict__ Aq,
    const unsigned short* __restrict__ Akv,
    const unsigned short* __restrict__ W,   // [z][N][K]
    void* __restrict__ Cb) {                // [z][M][N]
  constexpr int M = 4096, N = 2048, K = 2048, NT = K / 64;
  __shared__ char lds[147456];
  int z = blockIdx.z;
  const unsigned short* A = (z == 0) ? Aq : Akv;
  const unsigned short* Bt = W + (size_t)z * N * K;

  int wid = blockIdx.y * 16 + blockIdx.x;
  int nid = (wid & 7) * 32 + (wid >> 3);
  int bn = (nid & 15) * 128, bm = (nid >> 4) * 256;

  int tid = threadIdx.x, wave = tid >> 6, lane = tid & 63;
  int lr = lane & 15, lq = lane >> 4;
  int wr = wave >> 1, wc = wave & 1;

  auto STAGE_U = [&](int t, int buf, int which) {
    int k0 = (t & (NT - 1)) * 64;
    const unsigned short* src = (which < 2) ? A : Bt;
    int rbase = (which < 2) ? (bm + which * 128) : bn;
    char* dst0 = lds + buf * 49152 + which * 16384;
#pragma unroll
    for (int i = 0; i < 2; i++) {
      int o = i * 8192 + wave * 1024 + lane * 16;
      int row = o >> 7, colb = o & 127;
      int sc = colb ^ ((row & 7) << 4);
      __builtin_amdgcn_global_load_lds(
          (gas_cvp)(src + (size_t)(rbase + row) * K + k0 + (sc >> 1)),
          (las_vp)(dst0 + i * 8192 + wave * 1024), 16, 0, 0);
    }
  };
  auto LDA = [&](int buf, int m, int kk) -> bf16x8 {
    int row = wr * 64 + m * 16 + lr;
    int half = row >> 7, r = row & 127;
    int byt = r * 128 + (((kk * 4 + lq) ^ (r & 7)) << 4);
    return *(const bf16x8*)(lds + buf * 49152 + half * 16384 + byt);
  };
  auto LDB = [&](int buf, int n, int kk) -> bf16x8 {
    int row = wc * 64 + n * 16 + lr;
    int byt = row * 128 + (((kk * 4 + lq) ^ (row & 7)) << 4);
    return *(const bf16x8*)(lds + buf * 49152 + 32768 + byt);
  };

  f32x4 acc[4][4] = {};
  bf16x8 aA[2][2], bB[4][2];

  auto MFMA_H = [&](int mg) {
#pragma unroll
    for (int kk = 0; kk < 2; kk++)
#pragma unroll
      for (int mm = 0; mm < 2; mm++)
#pragma unroll
        for (int nn = 0; nn < 4; nn++)
          acc[mg * 2 + mm][nn] = __builtin_amdgcn_mfma_f32_16x16x32_bf16(
              aA[mm][kk], bB[nn][kk], acc[mg * 2 + mm][nn], 0, 0, 0);
  };
  auto PHASE_SYNC = [&]() {
    __builtin_amdgcn_s_barrier();
    asm volatile("s_waitcnt lgkmcnt(0)" ::: "memory");
    __builtin_amdgcn_sched_barrier(0);
    __builtin_amdgcn_s_setprio(1);
  };
  auto PHASE_END = [&]() {
    __builtin_amdgcn_s_setprio(0);
    __builtin_amdgcn_s_barrier();
  };

  STAGE_U(0, 0, 0); STAGE_U(0, 0, 1); STAGE_U(0, 0, 2);
  STAGE_U(1, 1, 0); STAGE_U(1, 1, 1); STAGE_U(1, 1, 2);
  asm volatile("s_waitcnt vmcnt(6)" ::: "memory");
  __builtin_amdgcn_sched_barrier(0);
  __builtin_amdgcn_s_barrier();

  int cur = 0;
  for (int T = 0; T < NT; T++) {
    int t2 = (T + 2) & (NT - 1);
    int b2 = cur + 2; if (b2 >= 3) b2 -= 3;
#pragma unroll
    for (int kk = 0; kk < 2; kk++) {
#pragma unroll
      for (int mm = 0; mm < 2; mm++) aA[mm][kk] = LDA(cur, mm, kk);
#pragma unroll
      for (int nn = 0; nn < 4; nn++) bB[nn][kk] = LDB(cur, nn, kk);
    }
    STAGE_U(t2, b2, 2); STAGE_U(t2, b2, 0);
    PHASE_SYNC(); MFMA_H(0); PHASE_END();

#pragma unroll
    for (int kk = 0; kk < 2; kk++)
#pragma unroll
      for (int mm = 0; mm < 2; mm++) aA[mm][kk] = LDA(cur, 2 + mm, kk);
    STAGE_U(t2, b2, 1);
    asm volatile("s_waitcnt vmcnt(6)" ::: "memory");
    __builtin_amdgcn_sched_barrier(0);
    PHASE_SYNC(); MFMA_H(1); PHASE_END();

    cur++; if (cur == 3) cur = 0;
  }

#pragma unroll
  for (int m = 0; m < 4; m++)
#pragma unroll
    for (int n = 0; n < 4; n++) {
      int row0 = bm + wr * 64 + m * 16 + lq * 4;
      int col = bn + wc * 64 + n * 16 + lr;
      if (BF16OUT) {
        unsigned short* C = (unsigned short*)Cb + (size_t)z * M * N;
#pragma unroll
        for (int r = 0; r < 4; r++)
          C[(size_t)(row0 + r) * N + col] = f2bf(acc[m][n][r]);
      } else {
        float* C = (float*)Cb + (size_t)z * M * N;
#pragma unroll
        for (int r = 0; r < 4; r++)
          C[(size_t)(row0 + r) * N + col] = acc[m][n][r];
      }
    }
}

// ---------- causal flash attention, swapped-QK^T in-register softmax ----------
__global__ __launch_bounds__(512, 1) void attn_kernel(const unsigned short* __restrict__ Qb,
                                                      const unsigned short* __restrict__ Kb,
                                                      const unsigned short* __restrict__ Vt,
                                                      unsigned short* __restrict__ ctx) {
  __shared__ char lds[65536];   // dbuf: [2][ K 16KB | V^T 16KB ]
  int d = blockIdx.x + 8 * (blockIdx.y + 16 * blockIdx.z);
  int jlo = (d >> 3) & 7;
  int hb = (d & 7) * 4 + (d >> 6);
  int h = hb & 15, b = hb >> 4;

  int tid = threadIdx.x, wave = tid >> 6, lane = tid & 63;
  int lr = lane & 15, lq = lane >> 4;
  int grp = wave >> 2, wsub = wave & 3;
  int qtile = grp ? (15 - jlo) : jlo;
  int qw = qtile * 128 + wsub * 32;
  int nt = 2 * (15 - jlo) + 2;

  const unsigned short* Qp = Qb + (size_t)b * S_LEN * DMODEL + (size_t)h * HDIM;
  const unsigned short* Kp = Kb + (size_t)b * S_LEN * DMODEL + (size_t)h * HDIM;
  const unsigned short* Vp = Vt + (size_t)(b * NH + h) * HDIM * S_LEN;

  bf16x8 qa[2][4];
#pragma unroll
  for (int mi = 0; mi < 2; mi++)
#pragma unroll
    for (int kf = 0; kf < 4; kf++)
      qa[mi][kf] = *(const bf16x8*)(Qp + (size_t)(qw + mi * 16 + lr) * DMODEL + kf * 32 + lq * 8);

  f32x4 o[2][8] = {};
  float mrow[2] = {-1e30f, -1e30f};
  float lsum[2] = {0.f, 0.f};

  auto STAGE = [&](int tt, int bsel) {
    int kk0 = tt * 64;
#pragma unroll
    for (int i = 0; i < 2; i++) {
      int o_ = wave * 2048 + i * 1024 + lane * 16;
      int row = o_ >> 8, colb = o_ & 255;
      int sc_ = colb ^ ((row & 7) << 4);
      __builtin_amdgcn_global_load_lds(
          (gas_cvp)(Kp + (size_t)(kk0 + row) * DMODEL + (sc_ >> 1)),
          (las_vp)(lds + bsel * 32768 + wave * 2048 + i * 1024), 16, 0, 0);
    }
#pragma unroll
    for (int i = 0; i < 2; i++) {
      int o_ = wave * 2048 + i * 1024 + lane * 16;
      int row = o_ >> 7, colb = o_ & 127;
      int sc_ = colb ^ ((row & 7) << 4);
      __builtin_amdgcn_global_load_lds(
          (gas_cvp)(Vp + (size_t)row * S_LEN + kk0 + (sc_ >> 1)),
          (las_vp)(lds + bsel * 32768 + 16384 + wave * 2048 + i * 1024), 16, 0, 0);
    }
  };

  STAGE(0, 0);
  __syncthreads();

  for (int t = 0; t < nt; t++) {
    int cur = t & 1;
    int k0 = t * 64;
    if (t + 1 < nt) STAGE(t + 1, cur ^ 1);

    bool active = (k0 <= qw + 31);
    if (active) {
      const char* kbb = lds + cur * 32768;
      f32x4 sf[2][4] = {};
#pragma unroll
      for (int kf = 0; kf < 4; kf++) {
        bf16x8 kbf[4];
#pragma unroll
        for (int nf = 0; nf < 4; nf++) {
          int row = nf * 16 + lr;
          int colb = kf * 64 + lq * 16;
          kbf[nf] = *(const bf16x8*)(kbb + row * 256 + (colb ^ ((row & 7) << 4)));
        }
#pragma unroll
        for (int nf = 0; nf < 4; nf++)
#pragma unroll
          for (int mi = 0; mi < 2; mi++)
            sf[mi][nf] = __builtin_amdgcn_mfma_f32_16x16x32_bf16(kbf[nf], qa[mi][kf], sf[mi][nf], 0, 0, 0);
      }

      if (k0 + 63 > qw) {
#pragma unroll
        for (int mi = 0; mi < 2; mi++) {
          int q = qw + mi * 16 + lr;
#pragma unroll
          for (int nf = 0; nf < 4; nf++)
#pragma unroll
            for (int r = 0; r < 4; r++)
              if (k0 + nf * 16 + lq * 4 + r > q) sf[mi][nf][r] = -1e30f;
        }
      }

      float vmax[2];
#pragma unroll
      for (int mi = 0; mi < 2; mi++) {
        float v = sf[mi][0][0];
#pragma unroll
        for (int nf = 0; nf < 4; nf++)
#pragma unroll
          for (int r = 0; r < 4; r++) v = fmaxf(v, sf[mi][nf][r]);
        v = fmaxf(v, __shfl_xor(v, 16));
        v = fmaxf(v, __shfl_xor(v, 32));
        vmax[mi] = v;
      }
      bool need = (vmax[0] > mrow[0] + 8.f) || (vmax[1] > mrow[1] + 8.f);
      if (__any(need)) {
#pragma unroll
        for (int mi = 0; mi < 2; mi++) {
          float mn = fmaxf(mrow[mi], vmax[mi]);
          float al = __expf(mrow[mi] - mn);
          mrow[mi] = mn;
          lsum[mi] *= al;
#pragma unroll
          for (int ff = 0; ff < 8; ff++) o[mi][ff] *= al;
        }
      }
#pragma unroll
      for (int mi = 0; mi < 2; mi++) {
        float rs = 0.f;
#pragma unroll
        for (int nf = 0; nf < 4; nf++)
#pragma unroll
          for (int r = 0; r < 4; r++) {
            float p = __expf(sf[mi][nf][r] - mrow[mi]);
            sf[mi][nf][r] = p;
            rs += p;
          }
        rs += __shfl_xor(rs, 16);
        rs += __shfl_xor(rs, 32);
        lsum[mi] += rs;
      }

      const char* vbb = lds + cur * 32768 + 16384;
      bool hi = (lane >= 32);
      bool odd = (lq & 1);
#pragma unroll
      for (int c = 0; c < 2; c++) {
        bf16x8 pfrag[2];
#pragma unroll
        for (int mi = 0; mi < 2; mi++) {
          unsigned int A0 = cvt_pk_bf16(sf[mi][2 * c][0], sf[mi][2 * c][1]);
          unsigned int A1 = cvt_pk_bf16(sf[mi][2 * c][2], sf[mi][2 * c][3]);
          unsigned int B0 = cvt_pk_bf16(sf[mi][2 * c + 1][0], sf[mi][2 * c + 1][1]);
          unsigned int B1 = cvt_pk_bf16(sf[mi][2 * c + 1][2], sf[mi][2 * c + 1][3]);
          unsigned int sA0 = (unsigned int)__shfl_xor((int)A0, 32);
          unsigned int sA1 = (unsigned int)__shfl_xor((int)A1, 32);
          unsigned int sB0 = (unsigned int)__shfl_xor((int)B0, 32);
          unsigned int sB1 = (unsigned int)__shfl_xor((int)B1, 32);
          unsigned int Y0f = hi ? sB0 : A0, Y0s = hi ? B0 : sA0;
          unsigned int Y1f = hi ? sB1 : A1, Y1s = hi ? B1 : sA1;
          unsigned int z0 = odd ? Y0f : Y0s, z1 = odd ? Y1f : Y1s;
          unsigned int w0 = (unsigned int)__shfl_xor((int)z0, 16);
          unsigned int w1 = (unsigned int)__shfl_xor((int)z1, 16);
          int4 fr;
          fr.x = (int)(odd ? w0 : Y0f);
          fr.y = (int)(odd ? w1 : Y1f);
          fr.z = (int)(odd ? Y0s : w0);
          fr.w = (int)(odd ? Y1s : w1);
          pfrag[mi] = __builtin_bit_cast(bf16x8, fr);
        }
#pragma unroll
        for (int ff = 0; ff < 8; ff++) {
          int row = ff * 16 + lr;
          int colb = c * 64 + lq * 16;
          bf16x8 vb = *(const bf16x8*)(vbb + row * 128 + (colb ^ ((row & 7) << 4)));
#pragma unroll
          for (int mi = 0; mi < 2; mi++)
            o[mi][ff] = __builtin_amdgcn_mfma_f32_16x16x32_bf16(vb, pfrag[mi], o[mi][ff], 0, 0, 0);
        }
      }
    }

    __syncthreads();
  }

#pragma unroll
  for (int mi = 0; mi < 2; mi++) {
    float inv = 1.0f / lsum[mi];
    size_t rb = ((size_t)b * S_LEN + qw + mi * 16 + lr) * DMODEL + h * HDIM;
#pragma unroll
    for (int ff = 0; ff < 8; ff++) {
      unsigned int u0 = cvt_pk_bf16(o[mi][ff][0] * inv, o[mi][ff][1] * inv);
      unsigned int u1 = cvt_pk_bf16(o[mi][ff][2] * inv, o[mi][ff][3] * inv);
      *(uint2*)(ctx + rb + ff * 16 + lq * 4) = make_uint2(u0, u1);
    }
  }
}

extern "C" void kernel_launch(void* const* d_in, const int* in_sizes, int n_in,
                              void* d_out, int out_size, void* d_ws, size_t ws_size,
                              hipStream_t stream) {
  const float* inq  = (const float*)d_in[0];
  const float* inkv = (const float*)d_in[1];
  const float* wq   = (const float*)d_in[2];
  const float* wk   = (const float*)d_in[3];
  const float* wv   = (const float*)d_in[4];
  const float* wo   = (const float*)d_in[5];
  float* out = (float*)d_out;

  char* ws = (char*)d_ws;
  const size_t MB = 1ull << 20;
  unsigned short* xq  = (unsigned short*)(ws);             // 16 MB (reused as Qb)
  unsigned short* xkv = (unsigned short*)(ws + 16 * MB);   // 16 MB (reused as Kb)
  unsigned short* wqt = (unsigned short*)(ws + 32 * MB);   // 8 MB
  unsigned short* wot = (unsigned short*)(ws + 56 * MB);   // 8 MB (wqt..wot contiguous)
  float2* sc          = (float2*)(ws + 64 * MB);           // 1 MB
  unsigned short* projb = (unsigned short*)(ws + 66 * MB); // 48 MB (Q,K,V bf16)
  unsigned short* Vt   = (unsigned short*)(ws + 114 * MB); // 16 MB
  unsigned short* ctxb = (unsigned short*)(ws + 130 * MB); // 16 MB
  unsigned short* Qb = xq;    // xq dead after proj GEMM
  unsigned short* Kb = xkv;   // xkv dead after proj GEMM

  const int n4 = (2 * S_LEN * DMODEL) / 4;
  cvt_kernel<<<n4 / 256, 256, 0, stream>>>((const float4*)inq, (ushort4*)xq, n4);
  cvt_kernel<<<n4 / 256, 256, 0, stream>>>((const float4*)inkv, (ushort4*)xkv, n4);

  wtrans4_kernel<<<dim3(32, 32, 4), 256, 0, stream>>>(wq, wk, wv, wo, wqt);

  sincos_kernel<<<(S_LEN * 64) / 256, 256, 0, stream>>>(sc);

  const float qscale = 0.08838834764831845f;  // 1/sqrt(128)
  unsigned short* projQ = projb;
  unsigned short* projK = projb + (size_t)4096 * 2048;
  unsigned short* projV = projb + (size_t)2 * 4096 * 2048;

  // all three projections in one dispatch (z = op); 384 blocks
  gemm256v2_kernel<true><<<dim3(8, 16, 3), 512, 0, stream>>>(xq, xkv, wqt, (void*)projb);

  rope8_kernel<<<dim3(2048, 1, 2), 256, 0, stream>>>(projQ, projK, sc, Qb, Kb, qscale);
  vtrans_kernel<<<dim3(2, 32, 32), 256, 0, stream>>>(projV, Vt);

  attn_kernel<<<dim3(8, NH, 2), 512, 0, stream>>>(Qb, Kb, Vt, ctxb);

  // output projection: 256 blocks = 1/CU (256x128 tile)
  gemm3b_kernel<false><<<dim3(16, 16, 1), 512, 0, stream>>>(ctxb, ctxb, wot, (void*)out);
}